// Round 4
// baseline (2403.345 us; speedup 1.0000x reference)
//
#include <hip/hip_runtime.h>
#include <hip/hip_bf16.h>
#include <stdint.h>

// ---------------- problem constants ----------------
#define ORIGV 19986
#define NEWV  37964
#define FACT  1024
#define DIM   768
#define BATCH 4096
#define NEGK  5
#define NPADC 20224     // 79*256 padded ORIG (k-dim of gemm2, n-dim of gemm1)
#define NT1   79        // gemm1 N tiles (256)
#define NKT1  16        // gemm1 K tiles (1024/64)
#define NKT2  316       // gemm2 K tiles (20224/64)
#define MAXSLOTS 28672  // 112*256 worst-case unique new ids
#define SHIFTC 300.0f

typedef unsigned short u16;
typedef __attribute__((ext_vector_type(8))) short short8;
typedef __attribute__((ext_vector_type(4))) float f32x4;

__device__ __forceinline__ u16 f2bf(float f) {
  uint32_t u = __builtin_bit_cast(uint32_t, f);
  u = (u + 0x7FFFu + ((u >> 16) & 1u)) >> 16;
  return (u16)u;
}

// ---------------- prepass kernels ----------------

__global__ void k_mark(const int* __restrict__ in_ids, const int* __restrict__ pos_ids,
                       const int* __restrict__ neg_ids, int* __restrict__ rowmap) {
  int i = blockIdx.x * blockDim.x + threadIdx.x;
  int id;
  if (i < BATCH) id = in_ids[i];
  else if (i < 2 * BATCH) id = pos_ids[i - BATCH];
  else if (i < 2 * BATCH + BATCH * NEGK) id = neg_ids[i - 2 * BATCH];
  else return;
  if (id >= ORIGV) rowmap[id - ORIGV] = 1;
}

__global__ void k_compact(int* __restrict__ rowmap, int* __restrict__ list,
                          int* __restrict__ count) {
  int r = blockIdx.x * blockDim.x + threadIdx.x;
  if (r >= NEWV) return;
  if (rowmap[r]) {
    int s = atomicAdd(count, 1);
    list[s] = r;
    rowmap[r] = s + 1;
  }
}

// A_W_2 [FACT][ORIGV] f32 -> A2t [NPADC][FACT] bf16 (zero pad rows >= ORIGV)
__global__ void k_transA2(const float* __restrict__ A2, u16* __restrict__ A2t) {
  __shared__ float tile[32][33];
  int tx = threadIdx.x & 31, ty = threadIdx.x >> 5;
  int r0 = blockIdx.x * 32;  // dst row (ORIG axis)
  int c0 = blockIdx.y * 32;  // dst col (FACT axis)
#pragma unroll
  for (int i = 0; i < 4; ++i) {
    int cc = ty + i * 8;
    int rr = r0 + tx;
    tile[cc][tx] = (rr < ORIGV) ? A2[(long)(c0 + cc) * ORIGV + rr] : 0.f;
  }
  __syncthreads();
#pragma unroll
  for (int i = 0; i < 4; ++i) {
    int r = r0 + ty + i * 8;
    A2t[(long)r * FACT + c0 + tx] = f2bf(tile[tx][ty + i * 8]);
  }
}

// W [ORIGV][DIM] f32 -> Wt [DIM][NPADC] bf16 (zero pad cols >= ORIGV)
__global__ void k_transW(const float* __restrict__ W, u16* __restrict__ Wt) {
  __shared__ float tile[32][33];
  int tx = threadIdx.x & 31, ty = threadIdx.x >> 5;
  int r0 = blockIdx.x * 32;  // dst row (DIM axis, < 768)
  int c0 = blockIdx.y * 32;  // dst col (ORIG axis, up to NPADC)
#pragma unroll
  for (int i = 0; i < 4; ++i) {
    int cc = ty + i * 8;
    int sc = c0 + cc;   // ORIG index
    int sr = r0 + tx;   // DIM index
    tile[cc][tx] = (sc < ORIGV) ? W[(long)sc * DIM + sr] : 0.f;
  }
  __syncthreads();
#pragma unroll
  for (int i = 0; i < 4; ++i) {
    int r = r0 + ty + i * 8;
    int c = c0 + tx;
    Wt[(long)r * NPADC + c] = f2bf(tile[tx][ty + i * 8]);
  }
}

// gather+convert A_W_1 rows for needed slots -> A1g [MAXSLOTS][FACT] bf16 (zeros past count)
__global__ void k_gather(const float* __restrict__ A1, const int* __restrict__ list,
                         const int* __restrict__ count, u16* __restrict__ A1g) {
  int i = blockIdx.x * blockDim.x + threadIdx.x;
  int row = i >> 7;
  int c0 = (i & 127) * 8;
  short8 v = {0, 0, 0, 0, 0, 0, 0, 0};
  if (row < *count) {
    int r = list[row];
    const float* s = A1 + (long)r * FACT + c0;
    float4 f0 = *reinterpret_cast<const float4*>(s);
    float4 f1 = *reinterpret_cast<const float4*>(s + 4);
    v[0] = (short)f2bf(f0.x); v[1] = (short)f2bf(f0.y);
    v[2] = (short)f2bf(f0.z); v[3] = (short)f2bf(f0.w);
    v[4] = (short)f2bf(f1.x); v[5] = (short)f2bf(f1.y);
    v[6] = (short)f2bf(f1.z); v[7] = (short)f2bf(f1.w);
  }
  *reinterpret_cast<short8*>(A1g + (long)row * FACT + c0) = v;
}

// ---------------- GEMM core (512 thr, 8 waves 2Mx4N, 256^2 tile) ----------------
// K-tile (64) split into two 32-wide sub-steps. Per sub-step one stage-group
// (A 16KB + B 16KB = 4 global_load_lds/thread) is issued; 3 groups in flight;
// uniform s_waitcnt vmcnt(8) + single s_barrier per sub-step (counted-vmcnt
// pipeline, cover = 3 sub-steps). LDS regions: [buf2][A/B][khalf2] x 16KB = 128KB.
// Swizzle: 16B slot s in row r holds source k-slot s ^ ((r>>1)&3)  -> the wave's
// 64-lane ds_read_b128 pattern is a dense 1KB sweep (bank-balanced).

__device__ __forceinline__ void gload16(const u16* g, u16* l) {
  __builtin_amdgcn_global_load_lds((const __attribute__((address_space(1))) void*)g,
                                   (__attribute__((address_space(3))) void*)l, 16, 0, 0);
}

__device__ __forceinline__ short8 ds_read128(const u16* p) {
  short8 d;
  asm volatile("ds_read_b128 %0, %1"
               : "=v"(d)
               : "v"((const __attribute__((address_space(3))) u16*)p));
  return d;
}

template<int NKT, bool ALIN>
__device__ __forceinline__ void gemm_mainloop(
    const u16* __restrict__ Apanel,   // ALIN: tile base (32KB tiles); else row0 of A panel
    long apitch,
    const u16* __restrict__ Bpanel, long bpitch,
    u16* lds, int t, f32x4 (&acc)[8][4]) {
  const int lane = t & 63, w = t >> 6;
  const int wm = w >> 2, wn = w & 3;
  const int l15 = lane & 15, l4 = lane >> 4;
  // per-thread staging constants (chunk = 16B; 1024 chunks per 16KB region)
  const int c0 = t, c1 = t + 512;
  const int r0 = c0 >> 2, r1 = c1 >> 2;
  const int s0 = (c0 & 3) ^ ((r0 >> 1) & 3), s1 = (c1 & 3) ^ ((r1 >> 1) & 3);
  const long aoff0 = (long)r0 * apitch + s0 * 8, aoff1 = (long)r1 * apitch + s1 * 8;
  const long boff0 = (long)r0 * bpitch + s0 * 8, boff1 = (long)r1 * bpitch + s1 * 8;

  auto stage = [&](int g) {
    int gt = g >> 1, gk = g & 1, bsel = gt & 1;
    u16* la = lds + (size_t)(((bsel * 2 + 0) * 2 + gk) * 8192);
    u16* lb = lds + (size_t)(((bsel * 2 + 1) * 2 + gk) * 8192);
    long kb = (long)gt * 64 + gk * 32;
    if (ALIN) {
      const u16* ga = Apanel + (size_t)gt * 16384 + (size_t)gk * 8192;
      gload16(ga + c0 * 8, la + (size_t)(c0 & ~63) * 8);
      gload16(ga + c1 * 8, la + (size_t)(c1 & ~63) * 8);
    } else {
      gload16(Apanel + aoff0 + kb, la + (size_t)(c0 & ~63) * 8);
      gload16(Apanel + aoff1 + kb, la + (size_t)(c1 & ~63) * 8);
    }
    gload16(Bpanel + boff0 + kb, lb + (size_t)(c0 & ~63) * 8);
    gload16(Bpanel + boff1 + kb, lb + (size_t)(c1 & ~63) * 8);
  };

  stage(0); stage(1); stage(2);

  for (int s = 0; s < 2 * NKT; ++s) {
    asm volatile("s_waitcnt vmcnt(8)" ::: "memory");   // own oldest group landed
    asm volatile("s_barrier" ::: "memory");            // collectively: region (s) valid
    int g = s + 3; if (g >= 2 * NKT) g -= 2 * NKT;     // wrap re-stage: harmless, keeps count uniform
    stage(g);
    const int bsel = (s >> 1) & 1, ks = s & 1;
    const u16* Ar = lds + (size_t)(((bsel * 2 + 0) * 2 + ks) * 8192);
    const u16* Br = lds + (size_t)(((bsel * 2 + 1) * 2 + ks) * 8192);
    short8 af[8], bf[4];
#pragma unroll
    for (int mi = 0; mi < 8; ++mi) {
      int row = wm * 128 + mi * 16 + l15;
      af[mi] = ds_read128((const u16*)((const char*)Ar + row * 64 + ((l4 ^ ((row >> 1) & 3)) << 4)));
    }
#pragma unroll
    for (int nj = 0; nj < 4; ++nj) {
      int row = wn * 64 + nj * 16 + l15;
      bf[nj] = ds_read128((const u16*)((const char*)Br + row * 64 + ((l4 ^ ((row >> 1) & 3)) << 4)));
    }
    asm volatile("s_waitcnt lgkmcnt(0)" ::: "memory");
    __builtin_amdgcn_sched_barrier(0);
    __builtin_amdgcn_s_setprio(1);
#pragma unroll
    for (int mi = 0; mi < 8; ++mi)
#pragma unroll
      for (int nj = 0; nj < 4; ++nj)
        acc[mi][nj] = __builtin_amdgcn_mfma_f32_16x16x32_bf16(af[mi], bf[nj], acc[mi][nj], 0, 0, 0);
    __builtin_amdgcn_s_setprio(0);
  }
  // Drain pending LDS-DMA before the wave can exit: a wave reaching s_endpgm
  // with in-flight global_load_lds could corrupt a successor workgroup's LDS.
  asm volatile("s_waitcnt vmcnt(0)" ::: "memory");
}

// GEMM1: S = A1g x A2t^T; P = exp(S-300) -> swizzled 32KB tiles; row-sums -> denom.
__global__ __launch_bounds__(512, 2) void k_gemm1(const u16* __restrict__ A1g,
                                                  const u16* __restrict__ A2t,
                                                  u16* __restrict__ Pt,
                                                  float* __restrict__ denom,
                                                  const int* __restrict__ count,
                                                  int slot0, int rowsInChunk) {
  __shared__ __align__(16) u16 lds[65536];
  int t = threadIdx.x;
  int bx = blockIdx.x, by = blockIdx.y;
  if (bx * 256 >= rowsInChunk) return;
  int gs0 = slot0 + bx * 256;
  if (gs0 >= *count) return;
  int n0 = by * 256;
  f32x4 acc[8][4];
#pragma unroll
  for (int a = 0; a < 8; ++a)
#pragma unroll
    for (int b = 0; b < 4; ++b) acc[a][b] = (f32x4){0.f, 0.f, 0.f, 0.f};

  gemm_mainloop<NKT1, false>(A1g + (size_t)gs0 * FACT, FACT,
                             A2t + (size_t)n0 * FACT, FACT, lds, t, acc);

  const int lane = t & 63, w = t >> 6, wm = w >> 2, wn = w & 3;
  const int l15 = lane & 15, l4 = lane >> 4;
  int prow_base = bx * 256 + wm * 128;
#pragma unroll
  for (int mi = 0; mi < 8; ++mi) {
#pragma unroll
    for (int r = 0; r < 4; ++r) {
      int prow = prow_base + mi * 16 + l4 * 4 + r;
      int row = prow & 255;
      float rs = 0.f;
#pragma unroll
      for (int nj = 0; nj < 4; ++nj) {
        int kcol = n0 + wn * 64 + nj * 16 + l15;
        float p = __expf(acc[mi][nj][r] - SHIFTC);
        rs += p;
        size_t tbase = ((size_t)(prow >> 8) * NKT2 + (kcol >> 6)) * 32768;  // bytes
        uint32_t boff = (uint32_t)(((kcol >> 5) & 1) * 16384 + row * 64 +
                                   ((((kcol & 31) >> 3) ^ ((row >> 1) & 3)) << 4) + (kcol & 7) * 2);
        *(u16*)((char*)Pt + tbase + boff) = f2bf(p);
      }
      rs += __shfl_xor(rs, 1); rs += __shfl_xor(rs, 2);
      rs += __shfl_xor(rs, 4); rs += __shfl_xor(rs, 8);
      if (l15 == 0) atomicAdd(&denom[slot0 + prow], rs);
    }
  }
}

// GEMM2: O = P x Wt^T (N = 768). K = NPADC, A staged linearly from swizzled P tiles.
__global__ __launch_bounds__(512, 2) void k_gemm2(const u16* __restrict__ Pt,
                                                  const u16* __restrict__ Wt,
                                                  float* __restrict__ Obuf,
                                                  const int* __restrict__ count,
                                                  int slot0, int rowsInChunk) {
  __shared__ __align__(16) u16 lds[65536];
  int t = threadIdx.x;
  int bx = blockIdx.x, by = blockIdx.y;
  if (bx * 256 >= rowsInChunk) return;
  int gs0 = slot0 + bx * 256;
  if (gs0 >= *count) return;
  int n0 = by * 256;
  f32x4 acc[8][4];
#pragma unroll
  for (int a = 0; a < 8; ++a)
#pragma unroll
    for (int b = 0; b < 4; ++b) acc[a][b] = (f32x4){0.f, 0.f, 0.f, 0.f};

  gemm_mainloop<NKT2, true>(Pt + (size_t)bx * NKT2 * 16384, 0,
                            Wt + (size_t)n0 * NPADC, NPADC, lds, t, acc);

  const int lane = t & 63, w = t >> 6, wm = w >> 2, wn = w & 3;
  const int l15 = lane & 15, l4 = lane >> 4;
#pragma unroll
  for (int mi = 0; mi < 8; ++mi)
#pragma unroll
    for (int nj = 0; nj < 4; ++nj)
#pragma unroll
      for (int r = 0; r < 4; ++r) {
        int m = gs0 + wm * 128 + mi * 16 + l4 * 4 + r;
        int n = n0 + wn * 64 + nj * 16 + l15;
        Obuf[(size_t)m * DIM + n] = acc[mi][nj][r];
      }
}

// ---------------- scoring ----------------
__global__ __launch_bounds__(256) void k_score(const float* __restrict__ W,
                                               const float* __restrict__ Obuf,
                                               const float* __restrict__ denom,
                                               const int* __restrict__ rowmap,
                                               const int* __restrict__ in_ids,
                                               const int* __restrict__ pos_ids,
                                               const int* __restrict__ neg_ids,
                                               float* __restrict__ lossAcc) {
  int t = threadIdx.x;
  int b = blockIdx.x * 4 + (t >> 6);
  int lane = t & 63;

  auto resolve = [&](int id, const float*& p, float& sc) {
    if (id < ORIGV) { p = W + (long)id * DIM; sc = 1.f; }
    else {
      int s = rowmap[id - ORIGV] - 1;
      p = Obuf + (size_t)s * DIM;
      sc = 1.f / denom[s];  // softmax denominator folded into the bilinear score
    }
  };

  const float* pin; float scin;
  resolve(in_ids[b], pin, scin);
  float e[12];
#pragma unroll
  for (int j = 0; j < 12; ++j) e[j] = pin[lane + j * 64];

  auto wdot = [&](const float* q) {
    float d = 0.f;
#pragma unroll
    for (int j = 0; j < 12; ++j) d += e[j] * q[lane + j * 64];
#pragma unroll
    for (int off = 32; off > 0; off >>= 1) d += __shfl_xor(d, off);
    return d;
  };

  const float* pp; float scp;
  resolve(pos_ids[b], pp, scp);
  float ps = wdot(pp) * scin * scp;

  float sum5 = 0.f;
  for (int k = 0; k < NEGK; ++k) {
    const float* pn; float scn;
    resolve(neg_ids[b * NEGK + k], pn, scn);
    sum5 += wdot(pn) * scin * scn;
  }
  float posl = fmaxf(-ps, 0.f) + log1pf(__expf(-fabsf(ps)));
  float negl = fmaxf(sum5, 0.f) + log1pf(__expf(-fabsf(sum5)));
  if (lane == 0) atomicAdd(lossAcc, posl + negl);
}

__global__ void k_final(const float* __restrict__ lossAcc, float* __restrict__ out) {
  out[0] = lossAcc[0] * (1.f / (float)BATCH);
}

// ---------------- host launcher ----------------
extern "C" void kernel_launch(void* const* d_in, const int* in_sizes, int n_in,
                              void* d_out, int out_size, void* d_ws, size_t ws_size,
                              hipStream_t stream) {
  const float* W  = (const float*)d_in[0];
  const float* A1 = (const float*)d_in[1];
  const float* A2 = (const float*)d_in[2];
  const int* in_ids  = (const int*)d_in[3];
  const int* pos_ids = (const int*)d_in[4];
  const int* neg_ids = (const int*)d_in[5];
  float* out = (float*)d_out;

  char* ws = (char*)d_ws;
  size_t off = 0;
  auto alloc = [&](size_t bytes) -> char* {
    char* p = ws + off;
    off = (off + bytes + 255) & ~(size_t)255;
    return p;
  };
  u16*   A2t    = (u16*)alloc((size_t)NPADC * FACT * 2);       //  41.4 MB
  u16*   Wt     = (u16*)alloc((size_t)DIM * NPADC * 2);        //  31.1 MB
  u16*   A1g    = (u16*)alloc((size_t)MAXSLOTS * FACT * 2);    //  58.7 MB
  float* Obuf   = (float*)alloc((size_t)MAXSLOTS * DIM * 4);   //  88.1 MB
  float* denom  = (float*)alloc((size_t)MAXSLOTS * 4);
  int*   rowmap = (int*)alloc((size_t)NEWV * 4);
  int*   count  = (int*)alloc(4);
  float* lossAcc= (float*)alloc(4);
  int*   list   = (int*)alloc((size_t)MAXSLOTS * 4);
  u16*   P      = (u16*)(ws + off);                            // rest: swizzled P tiles
  size_t prem   = (ws_size > off) ? (ws_size - off) : 0;
  long chRows = (long)(prem / ((size_t)NPADC * 2));            // 40448 B per row
  chRows &= ~255L;
  if (chRows <= 0) return;  // workspace too small — visible clean failure
  if (chRows > MAXSLOTS) chRows = MAXSLOTS;
  int nch = (int)((MAXSLOTS + chRows - 1) / chRows);

  hipMemsetAsync(rowmap, 0, (size_t)NEWV * 4, stream);
  hipMemsetAsync(count, 0, 4, stream);
  hipMemsetAsync(lossAcc, 0, 4, stream);
  hipMemsetAsync(denom, 0, (size_t)MAXSLOTS * 4, stream);

  k_mark<<<(2 * BATCH + BATCH * NEGK + 255) / 256, 256, 0, stream>>>(in_ids, pos_ids, neg_ids, rowmap);
  k_compact<<<(NEWV + 255) / 256, 256, 0, stream>>>(rowmap, list, count);
  k_transA2<<<dim3(NPADC / 32, FACT / 32), 256, 0, stream>>>(A2, A2t);
  k_transW<<<dim3(DIM / 32, NPADC / 32), 256, 0, stream>>>(W, Wt);
  k_gather<<<(MAXSLOTS * 128) / 256, 256, 0, stream>>>(A1, list, count, A1g);

  for (int c = 0; c < nch; ++c) {
    int slot0 = c * (int)chRows;
    int rows = MAXSLOTS - slot0;
    if (rows > (int)chRows) rows = (int)chRows;
    // grid-x = 128 (multiple of 8): XCD = bx%8 -> mb-bands per XCD (L2 reuse);
    // gemm2's 3 N-blocks of the same mb land on the same XCD (P K-slab L2 sharing).
    k_gemm1<<<dim3(128, NT1), 512, 0, stream>>>(A1g, A2t, P, denom, count, slot0, rows);
    k_gemm2<<<dim3(128, 3), 512, 0, stream>>>(P, Wt, Obuf, count, slot0, rows);
  }

  k_score<<<BATCH / 4, 256, 0, stream>>>(W, Obuf, denom, rowmap, in_ids, pos_ids, neg_ids, lossAcc);
  k_final<<<1, 1, 0, stream>>>(lossAcc, out);
}